// Round 8
// baseline (4874.049 us; speedup 1.0000x reference)
//
#include <hip/hip_runtime.h>
#include <math.h>

#define B_ 8
#define P_ 8192
#define N_ 65536
#define K_ 16
#define EPS_ 1e-5f
#define NC_ 64                  // x columns per batch
#define NY_ 64                  // y cells per column
#define CSC 1.28f               // 64 / 50
#define SLACK 0.999999f         // certified under-estimate slack

typedef unsigned long long ull;

__device__ __forceinline__ int b64(float v) {
    int b = (int)(v * CSC);
    return b > 63 ? 63 : (b < 0 ? 0 : b);
}

static __device__ __forceinline__ ull shflx_u64(ull v, int m) {
    int lo = (int)(v & 0xffffffffu), hi = (int)(v >> 32);
    lo = __shfl_xor(lo, m, 64); hi = __shfl_xor(hi, m, 64);
    return ((ull)(unsigned)hi << 32) | (unsigned)lo;
}

// ============================ 2D binning ===================================
__global__ __launch_bounds__(256) void init5(int* counts, int* cursors,
                                             int* xminI, int* xmaxI,
                                             int* yminI, int* ymaxI) {
    int i = blockIdx.x * 256 + threadIdx.x;       // 32768 cells
    counts[i] = 0; cursors[i] = 0;
    xminI[i] = 0x7F7FFFFF; xmaxI[i] = 0x80000000; // non-neg floats: int order == float order
    yminI[i] = 0x7F7FFFFF; ymaxI[i] = 0x80000000;
}

__global__ __launch_bounds__(256) void count5(const float* __restrict__ vc,
                                              int* counts, int* xminI, int* xmaxI,
                                              int* yminI, int* ymaxI) {
    int q = blockIdx.x * 256 + threadIdx.x;
    float4 p = ((const float4*)vc)[q];            // [batch, x, y, z]
    int b = q >> 13;
    int e = (b << 12) + (b64(p.y) << 6) + b64(p.z);
    atomicAdd(&counts[e], 1);
    atomicMin(&xminI[e], __float_as_int(p.y));
    atomicMax(&xmaxI[e], __float_as_int(p.y));
    atomicMin(&yminI[e], __float_as_int(p.z));
    atomicMax(&ymaxI[e], __float_as_int(p.z));
}

__global__ __launch_bounds__(1024) void scan5(const int* __restrict__ counts, int* off) {
    __shared__ int sm[1024];
    int b = blockIdx.x, t = threadIdx.x;
    int base = (b << 12) + (t << 2);
    int c0 = counts[base], c1 = counts[base+1], c2 = counts[base+2], c3 = counts[base+3];
    int tot = c0 + c1 + c2 + c3;
    sm[t] = tot; __syncthreads();
    for (int s = 1; s < 1024; s <<= 1) {
        int u = sm[t]; int v = (t >= s) ? sm[t - s] : 0;
        __syncthreads(); sm[t] = u + v; __syncthreads();
    }
    int excl = sm[t] - tot;
    int ob = b * 4097 + (t << 2);
    off[ob]   = excl;
    off[ob+1] = excl + c0;
    off[ob+2] = excl + c0 + c1;
    off[ob+3] = excl + c0 + c1 + c2;
    if (t == 1023) off[b * 4097 + 4096] = sm[t];
}

__global__ __launch_bounds__(256) void bounds5(const int* __restrict__ counts,
                                               const int* __restrict__ xminI, const int* __restrict__ xmaxI,
                                               const int* __restrict__ yminI, const int* __restrict__ ymaxI,
                                               float* ylub, float* yglb,
                                               float* colxmin, float* colxmax) {
    int i = blockIdx.x * 256 + threadIdx.x;
    if (i >= B_ * NC_) return;
    int b = i >> 6, c = i & 63;
    int base = (b << 12) + (c << 6);
    float run = -1e30f, cxm = -1e30f, cxn = 1e30f;
    for (int yb = 0; yb < NY_; ++yb) {
        int ct = counts[base + yb];
        float ym = ct ? __int_as_float(ymaxI[base + yb]) : -1e30f;
        run = fmaxf(run, ym);
        ylub[base + yb] = run;
        if (ct) {
            cxm = fmaxf(cxm, __int_as_float(xmaxI[base + yb]));
            cxn = fminf(cxn, __int_as_float(xminI[base + yb]));
        }
    }
    run = 1e30f;
    for (int yb = NY_ - 1; yb >= 0; --yb) {
        int ct = counts[base + yb];
        float ym = ct ? __int_as_float(yminI[base + yb]) : 1e30f;
        run = fminf(run, ym);
        yglb[base + yb] = run;
    }
    colxmax[(b << 6) + c] = cxm;
    colxmin[(b << 6) + c] = cxn;
}

__global__ void colpre(const float* __restrict__ colxmin, const float* __restrict__ colxmax,
                       float* colxlub, float* colxglb) {
    int b = threadIdx.x;
    if (b < B_) {
        float run = -1e30f;
        for (int c = 0; c < NC_; ++c) { run = fmaxf(run, colxmax[(b<<6)+c]); colxlub[(b<<6)+c] = run; }
        run = 1e30f;
        for (int c = NC_ - 1; c >= 0; --c) { run = fminf(run, colxmin[(b<<6)+c]); colxglb[(b<<6)+c] = run; }
    }
}

__global__ __launch_bounds__(256) void scatter5(const float* __restrict__ vc,
                                                const int* __restrict__ off,
                                                int* cursors, float4* pos4s) {
    int q = blockIdx.x * 256 + threadIdx.x;
    float4 p = ((const float4*)vc)[q];
    int b = q >> 13;
    int e = (b << 12) + (b64(p.y) << 6) + b64(p.z);
    int slot = off[b * 4097 + (e & 4095)] + atomicAdd(&cursors[e], 1);
    pos4s[(b << 13) + slot] = make_float4(p.y, p.z, p.w, __int_as_float(q));
}

// ============================ knn6: one WAVE per query =====================
// All control flow wave-uniform (cell walk, tau, bounds); lanes do pure
// data-parallel candidate rounds (coalesced float4 loads, no LDS, no
// barriers). Selection: 16x wave-min-extract on u64 (d_bits<<32|idx) keys ->
// exact top_k incl. lowest-index ties. Phase 1: home column -> tau (16th of
// superset >= tau_true). Phase 2: home rescan (d<=tau) + certified-slack cell
// expansion, hits round-robined over lanes; final extract-16 writes output.
// All index loops clamped -> bounded runtime even with garbage workspace.
__global__ __launch_bounds__(256) void knn6_kernel(
    const float4* __restrict__ pos4s,
    const int* __restrict__ off,
    const float* __restrict__ ylubA,
    const float* __restrict__ yglbA,
    const float* __restrict__ colxlub,
    const float* __restrict__ colxglb,
    unsigned short* __restrict__ idx_out,
    float* __restrict__ d2_out)
{
    const int lane = threadIdx.x & 63;
    const int slot = (blockIdx.x << 2) + (threadIdx.x >> 6);  // query slot (sorted order)
    const int bb   = slot >> 13;
    const float4* cp = pos4s + ((size_t)bb << 13);
    const int* offb = off + bb * 4097;
    const float* yl  = ylubA + (bb << 12);
    const float* yg  = yglbA + (bb << 12);
    const float* cxl = colxlub + (bb << 6);
    const float* cxg = colxglb + (bb << 6);

    const float4 me = cp[slot & (P_ - 1)];
    const float qx = me.x, qy = me.y, qz = me.z;
    const int qid = __float_as_int(me.w);
    const int qc = b64(qx), qyb = b64(qy);

    // home column range, clamped (robustness vs poisoned off)
    int j0 = offb[qc << 6], j1 = offb[(qc + 1) << 6];
    j0 = max(0, min(j0, P_)); j1 = max(j0, min(j1, P_)); j1 = min(j1, j0 + 384);

#define DIST6_(c_, d_)                                                      \
    float d_; {                                                             \
        float dx_ = __fsub_rn(qx, (c_).x);                                  \
        float dy_ = __fsub_rn(qy, (c_).y);                                  \
        float dz_ = __fsub_rn(qz, (c_).z);                                  \
        d_ = __fadd_rn(__fadd_rn(__fmul_rn(dx_,dx_), __fmul_rn(dy_,dy_)),   \
                       __fmul_rn(dz_,dz_));                                 \
    }
#define KEY6_(d_, c_) ( ((ull)(unsigned)__float_as_int(d_) << 32)           \
                      | (unsigned)(__float_as_int((c_).w) & 0xffff) )

    // ---- phase 1: home column keys -> KB (cap 6/lane), extract tau ----
    ull KB[6];
#pragma unroll
    for (int t = 0; t < 6; ++t) KB[t] = ~0ull;
    {
        int cb = 0;
        for (int j = j0 + lane; j < j1; j += 64) {
            float4 c_ = cp[j];
            DIST6_(c_, d_)
            ull key = KEY6_(d_, c_);
            if (cb < 6) {
#pragma unroll
                for (int t = 0; t < 6; ++t) if (cb == t) KB[t] = key;
            }
            ++cb;
        }
    }
    float tau;
    {
        ull last = ~0ull;
        for (int i = 0; i < K_; ++i) {
            ull m = KB[0];
#pragma unroll
            for (int t = 1; t < 6; ++t) m = m < KB[t] ? m : KB[t];
#pragma unroll
            for (int s = 1; s < 64; s <<= 1) {
                ull o = shflx_u64(m, s);
                m = o < m ? o : m;
            }
#pragma unroll
            for (int t = 0; t < 6; ++t) if (KB[t] == m) KB[t] = ~0ull;
            last = m;
        }
        tau = __uint_as_float((unsigned)(last >> 32));
    }

    // ---- phase 2: pool = home hits + expansion hits (KA, cap 12/lane) ----
    ull KA[12];
#pragma unroll
    for (int t = 0; t < 12; ++t) KA[t] = ~0ull;
    int cnt = 0;

#define STORE6_(key_) {                                                     \
        if (cnt < 12) {                                                     \
            _Pragma("unroll")                                               \
            for (int t = 0; t < 12; ++t) if (cnt == t) KA[t] = (key_);      \
            ++cnt;                                                          \
        }                                                                   \
    }

    for (int j = j0 + lane; j < j1; j += 64) {
        float4 c_ = cp[j];
        DIST6_(c_, d_)
        if (d_ <= tau) { ull key = KEY6_(d_, c_); STORE6_(key) }
    }

    unsigned rr = 0;   // running point counter -> round-robin lane mapping
#define SCELL6_(bi_) {                                                      \
        int a_ = offb[bi_], b_ = offb[(bi_) + 1];                           \
        a_ = max(0, min(a_, P_)); b_ = max(a_, min(b_, P_));                \
        int cn_ = min(b_ - a_, 64);                                         \
        int my_ = (int)((unsigned)(lane - rr) & 63u);                       \
        if (my_ < cn_) {                                                    \
            float4 c_ = cp[a_ + my_];                                       \
            DIST6_(c_, d_)                                                  \
            if (d_ <= tau) { ull key = KEY6_(d_, c_); STORE6_(key) }        \
        }                                                                   \
        rr += (unsigned)cn_;                                                \
    }

#define COLSCAN6_(cc_, dx2u_) {                                             \
        SCELL6_(((cc_) << 6) + qyb)                                         \
        for (int yb = qyb - 1; yb >= 0; --yb) {                             \
            float t_ = __fsub_rn(qy, yl[((cc_) << 6) + yb]);                \
            float dy2_ = t_ > 0.f ? __fmul_rn(__fmul_rn(t_,t_), SLACK) : 0.f; \
            if (__fmul_rn(__fadd_rn(dx2u_, dy2_), SLACK) > tau) break;      \
            SCELL6_(((cc_) << 6) + yb)                                      \
        }                                                                   \
        for (int yb = qyb + 1; yb < NY_; ++yb) {                            \
            float t_ = __fsub_rn(yg[((cc_) << 6) + yb], qy);                \
            float dy2_ = t_ > 0.f ? __fmul_rn(__fmul_rn(t_,t_), SLACK) : 0.f; \
            if (__fmul_rn(__fadd_rn(dx2u_, dy2_), SLACK) > tau) break;      \
            SCELL6_(((cc_) << 6) + yb)                                      \
        }                                                                   \
    }

    {
        int cl = qc - 1, cr = qc + 1;
        for (int guard = 0; guard < 2 * NC_; ++guard) {
            bool needL = false, needR = false;
            float dxl = 0.f, dxr = 0.f;
            if (cl >= 0) {
                float t_ = __fsub_rn(qx, cxl[cl]);
                dxl = t_ > 0.f ? __fmul_rn(__fmul_rn(t_,t_), SLACK) : 0.f;
                needL = !(dxl > tau);
            }
            if (cr < NC_) {
                float t_ = __fsub_rn(cxg[cr], qx);
                dxr = t_ > 0.f ? __fmul_rn(__fmul_rn(t_,t_), SLACK) : 0.f;
                needR = !(dxr > tau);
            }
            if (!needL && !needR) break;
            if (needL) { COLSCAN6_(cl, dxl) --cl; }
            if (needR) { COLSCAN6_(cr, dxr) ++cr; }
        }
    }

    // ---- final: extract 16 (exact (d, idx) lex order), lane 0 writes ----
    for (int i = 0; i < K_; ++i) {
        ull m = KA[0];
#pragma unroll
        for (int t = 1; t < 12; ++t) m = m < KA[t] ? m : KA[t];
#pragma unroll
        for (int s = 1; s < 64; s <<= 1) {
            ull o = shflx_u64(m, s);
            m = o < m ? o : m;
        }
        if (lane == 0) {
            d2_out[(size_t)qid * K_ + i] = __uint_as_float((unsigned)(m >> 32));
            idx_out[(size_t)qid * K_ + i] = (unsigned short)(m & 0xffffu);
        }
#pragma unroll
        for (int t = 0; t < 12; ++t) if (KA[t] == m) KA[t] = ~0ull;
    }
#undef DIST6_
#undef KEY6_
#undef STORE6_
#undef SCELL6_
#undef COLSCAN6_
}

// ============================ edgeconv (unchanged) =========================
static __device__ inline double shfl_xor_dbl(double v, int mask) {
    long long b = __double_as_longlong(v);
    int lo = (int)(b & 0xffffffffLL);
    int hi = (int)(b >> 32);
    lo = __shfl_xor(lo, mask, 64);
    hi = __shfl_xor(hi, mask, 64);
    return __longlong_as_double(((long long)hi << 32) | (unsigned long long)(unsigned int)lo);
}

template<int CIN, int COUT, bool PHA>
__global__ __launch_bounds__(256) void edge_kernel(
    const float* __restrict__ x,
    const unsigned short* __restrict__ idx,
    const float* __restrict__ d2,
    const float* __restrict__ W,
    const float* __restrict__ bias,
    const float* __restrict__ wk,
    const float* __restrict__ wq,
    const float* __restrict__ acoef,
    const float* __restrict__ ccoef,
    double* __restrict__ gsum,
    double* __restrict__ gsumsq,
    float* __restrict__ out,
    int niter)
{
    constexpr int LOGC = (COUT == 64) ? 6 : 5;
    constexpr int GPW  = 64 / COUT;
    constexpr int GPB  = 4 * GPW;
    constexpr int C4   = CIN / 4;
    constexpr int SJ   = (K_ + 1) * CIN;
    constexpr int HTS  = COUT + 1;
    constexpr int HTN  = PHA ? 1 : (K_ * HTS);
    constexpr int PN   = PHA ? 1 : (K_ * K_);
    constexpr int KQN  = PHA ? 1 : (2 * K_);
    constexpr int SCN  = PHA ? 1 : K_;
    constexpr int PARTN= (!PHA && COUT == 64) ? 64 : 1;
    constexpr int WKQN = PHA ? 1 : (2 * COUT);

    const int tid  = threadIdx.x;
    const int wave = tid >> 6;
    const int lane = tid & 63;
    const int lo   = lane & (COUT - 1);
    const int grp  = lane >> LOGC;
    const int gidx = wave * GPW + grp;

    __shared__ __align__(16) float sj_s[GPB][SJ];
    __shared__ __align__(16) float hT_s[GPB][HTN];
    __shared__ __align__(16) float p_s[GPB][PN];
    __shared__ __align__(16) float kqv_s[GPB][KQN];
    __shared__ __align__(16) float rden_s[GPB][SCN];
    __shared__ __align__(16) float scal_s[GPB][SCN];
    __shared__ __align__(16) float part_s[GPB][PARTN];
    __shared__ __align__(16) float wkq_s[WKQN];

    float Wr[CIN], Ad[CIN];
#pragma unroll
    for (int c = 0; c < CIN; ++c) {
        float wl = W[lo * (2*CIN) + c];
        float wr = W[lo * (2*CIN) + CIN + c];
        Wr[c] = wr; Ad[c] = wl - wr;
    }
    const float b_s = bias[lo];

    float a_s = 0.f, c_s = 0.f;
    if constexpr (!PHA) {
        a_s = acoef[lo]; c_s = ccoef[lo];
        if (tid < COUT)            wkq_s[tid] = wk[tid];
        else if (tid < 2*COUT)     wkq_s[tid] = wq[tid - COUT];
    }
    __syncthreads();

    double lsum = 0.0, lsq = 0.0;
    const int g0      = blockIdx.x * GPB + gidx;
    const int gstride = gridDim.x * GPB;

    for (int it = 0; it < niter; ++it) {
        const int n = g0 + it * gstride;

        {
            const float4* xs  = (const float4*)x;
            float4*       sj4 = (float4*)sj_s[gidx];
            constexpr int TOT4 = (K_ + 1) * C4;
#pragma unroll
            for (int e0 = 0; e0 < TOT4; e0 += COUT) {
                int e = e0 + lo;
                if (e < TOT4) {
                    int r = e / C4;
                    int c = e - r * C4;
                    int row = (r < K_) ? (int)idx[n * K_ + r] : n;
                    sj4[e] = xs[row * C4 + c];
                }
            }
        }
        if constexpr (!PHA) {
            if (lo < K_) {
                float dis = sqrtf(d2[n * K_ + lo]);
                float e = __expf(-dis);
                scal_s[gidx][lo] = 2.0f * e / (1.0f + e);
            }
        }
        __syncthreads();

        const float* sj = sj_s[gidx];
        float t0 = b_s;
#pragma unroll
        for (int c = 0; c < C4; ++c) {
            float4 v = ((const float4*)(sj + K_ * CIN))[c];
            t0 = fmaf(Ad[4*c  ], v.x, t0);
            t0 = fmaf(Ad[4*c+1], v.y, t0);
            t0 = fmaf(Ad[4*c+2], v.z, t0);
            t0 = fmaf(Ad[4*c+3], v.w, t0);
        }
        float hn[K_];
#pragma unroll
        for (int k = 0; k < K_; ++k) {
            float acc = t0;
            const float4* xr = (const float4*)(sj + k * CIN);
#pragma unroll
            for (int c = 0; c < C4; ++c) {
                float4 v = xr[c];
                acc = fmaf(Wr[4*c  ], v.x, acc);
                acc = fmaf(Wr[4*c+1], v.y, acc);
                acc = fmaf(Wr[4*c+2], v.z, acc);
                acc = fmaf(Wr[4*c+3], v.w, acc);
            }
            float h = fmaxf(acc, 0.f);
            if constexpr (PHA) {
                double hd = (double)h;
                lsum += hd;
                lsq  = fma(hd, hd, lsq);
            } else {
                hn[k] = fmaf(a_s, h, c_s);
            }
        }

        if constexpr (!PHA) {
            float* hT = hT_s[gidx];
#pragma unroll
            for (int k = 0; k < K_; ++k) hT[k * HTS + lo] = hn[k];
            __syncthreads();

            const int kk   = lo & 15;
            const int role = lo >> 4;
            float av = 0.f;
            const float* hrow = hT + kk * HTS;
            int obase; const float* wv;
            if constexpr (COUT == 64) { obase = (role & 1) * 32; wv = wkq_s + ((role >> 1) ? COUT : 0); }
            else                      { obase = 0;               wv = wkq_s + (role ? COUT : 0); }
#pragma unroll
            for (int j = 0; j < 32; ++j)
                av = fmaf(hrow[obase + j], wv[obase + j], av);
            if constexpr (COUT == 64) {
                part_s[gidx][lo] = av;
                __syncthreads();
                if (lo < 16)      kqv_s[gidx][lo] = part_s[gidx][lo]      + part_s[gidx][lo + 16];
                else if (lo < 32) kqv_s[gidx][lo] = part_s[gidx][lo + 16] + part_s[gidx][lo + 32];
            } else {
                kqv_s[gidx][lo] = av;
            }
            __syncthreads();

            if (lo < K_) {
                const int qq = lo;
                const float qv = kqv_s[gidx][K_ + qq];
                float m = -__builtin_huge_valf();
#pragma unroll
                for (int k = 0; k < K_; ++k) m = fmaxf(m, kqv_s[gidx][k] * qv);
                float den = 0.f;
#pragma unroll
                for (int k = 0; k < K_; ++k) {
                    float e = __expf(kqv_s[gidx][k] * qv - m);
                    den += e;
                    p_s[gidx][k * K_ + qq] = e;
                }
                rden_s[gidx][qq] = 1.0f / den;
            }
            __syncthreads();

            float hq[K_];
#pragma unroll
            for (int qq = 0; qq < K_; ++qq) hq[qq] = 0.f;
#pragma unroll
            for (int k = 0; k < K_; ++k) {
                const float hnk = hn[k];
                const float4* p4 = (const float4*)(p_s[gidx] + k * K_);
#pragma unroll
                for (int j = 0; j < 4; ++j) {
                    float4 v = p4[j];
                    hq[4*j  ] = fmaf(hnk, v.x, hq[4*j  ]);
                    hq[4*j+1] = fmaf(hnk, v.y, hq[4*j+1]);
                    hq[4*j+2] = fmaf(hnk, v.z, hq[4*j+2]);
                    hq[4*j+3] = fmaf(hnk, v.w, hq[4*j+3]);
                }
            }
            float res = -__builtin_huge_valf();
#pragma unroll
            for (int j = 0; j < 4; ++j) {
                float4 sc = ((const float4*)scal_s[gidx])[j];
                float4 rd = ((const float4*)rden_s[gidx])[j];
                res = fmaxf(res, sc.x * (hq[4*j  ] * rd.x));
                res = fmaxf(res, sc.y * (hq[4*j+1] * rd.y));
                res = fmaxf(res, sc.z * (hq[4*j+2] * rd.z));
                res = fmaxf(res, sc.w * (hq[4*j+3] * rd.w));
            }
            out[n * COUT + lo] = res;
            __syncthreads();
        } else {
            __syncthreads();
        }
    }

    if constexpr (PHA) {
        if constexpr (COUT == 32) {
            lsum += shfl_xor_dbl(lsum, 32);
            lsq  += shfl_xor_dbl(lsq, 32);
        }
        __shared__ double redS[4][COUT];
        __shared__ double redQ[4][COUT];
        if (lane < COUT) { redS[wave][lane] = lsum; redQ[wave][lane] = lsq; }
        __syncthreads();
        if (tid < COUT) {
            double ss = redS[0][tid] + redS[1][tid] + redS[2][tid] + redS[3][tid];
            double qq = redQ[0][tid] + redQ[1][tid] + redQ[2][tid] + redQ[3][tid];
            atomicAdd(&gsum[tid], ss);
            atomicAdd(&gsumsq[tid], qq);
        }
    }
}

__global__ void finalize_kernel(const double* __restrict__ gsum, const double* __restrict__ gsumsq,
                                const float* __restrict__ gamma, const float* __restrict__ beta,
                                float* __restrict__ a, float* __restrict__ c, int cout)
{
    int o = threadIdx.x;
    if (o < cout) {
        const double inv = 1.0 / ((double)N_ * (double)K_);
        double mu  = gsum[o] * inv;
        double var = gsumsq[o] * inv - mu * mu;
        double rs  = 1.0 / sqrt(var + (double)EPS_);
        double av  = rs * (double)gamma[o];
        a[o] = (float)av;
        c[o] = (float)((double)beta[o] - mu * av);
    }
}

__global__ __launch_bounds__(256) void copy_vc(const float4* __restrict__ src,
                                               float4* __restrict__ dst) {
    int i = blockIdx.x * 256 + threadIdx.x;
    dst[i] = src[i];
}

extern "C" void kernel_launch(void* const* d_in, const int* in_sizes, int n_in,
                              void* d_out, int out_size, void* d_ws, size_t ws_size,
                              hipStream_t stream)
{
    const float* pillar = (const float*)d_in[0];
    const float* vc     = (const float*)d_in[1];
    const float* W0  = (const float*)d_in[2];
    const float* b0  = (const float*)d_in[3];
    const float* g0  = (const float*)d_in[4];
    const float* be0 = (const float*)d_in[5];
    const float* wk0 = (const float*)d_in[6];
    const float* wq0 = (const float*)d_in[7];
    const float* W1  = (const float*)d_in[8];
    const float* b1  = (const float*)d_in[9];
    const float* g1  = (const float*)d_in[10];
    const float* be1 = (const float*)d_in[11];
    const float* wk1 = (const float*)d_in[12];
    const float* wq1 = (const float*)d_in[13];

    // ---- workspace (< 16 MiB total) ----
    char* ws = (char*)d_ws;
    double* dsum = (double*)ws;                              // 2 KB @ 0
    double *s0 = dsum, *sq0 = dsum + 64, *s1 = dsum + 128, *sq1 = dsum + 192;
    float* coef = (float*)(ws + 4096);                       // 1 KB @ 4K
    float *a0 = coef, *c0 = coef + 64, *a1 = coef + 128, *c1 = coef + 192;
    unsigned short* idx = (unsigned short*)(ws + 8192);      // 2 MB
    float* d2  = (float*)(ws + 8192 + (size_t)N_*K_*2);      // 4 MB
    float* x1  = (float*)(ws + 8192 + (size_t)N_*K_*6);      // 8 MB
    size_t base2 = 8192 + (size_t)N_*K_*6 + (size_t)N_*32*4; // = 14 MB + 8 KB
    float4* pos4s = (float4*)(ws + base2);                   // 1 MB
    char* p2 = ws + base2 + (1u << 20);
    const size_t NB2 = (size_t)B_ * 4096;                    // 32768 cells
    int* counts  = (int*)p2;  p2 += NB2 * 4;                 // 128 KB
    int* cursors = (int*)p2;  p2 += NB2 * 4;
    int* off     = (int*)p2;  p2 += (size_t)B_ * 4097 * 4;   // ~128 KB
    int* xminI   = (int*)p2;  p2 += NB2 * 4;
    int* xmaxI   = (int*)p2;  p2 += NB2 * 4;
    int* yminI   = (int*)p2;  p2 += NB2 * 4;
    int* ymaxI   = (int*)p2;  p2 += NB2 * 4;
    float* ylubA = (float*)p2; p2 += NB2 * 4;
    float* yglbA = (float*)p2; p2 += NB2 * 4;
    float* colxmin = (float*)p2; p2 += B_ * NC_ * 4;
    float* colxmax = (float*)p2; p2 += B_ * NC_ * 4;
    float* colxlub = (float*)p2; p2 += B_ * NC_ * 4;
    float* colxglb = (float*)p2; p2 += B_ * NC_ * 4;

    float* xout = (float*)d_out;
    float* vout = xout + (size_t)N_ * 64;

    hipMemsetAsync(dsum, 0, 2048, stream);
    init5<<<NB2 / 256, 256, 0, stream>>>(counts, cursors, xminI, xmaxI, yminI, ymaxI);
    count5<<<N_ / 256, 256, 0, stream>>>(vc, counts, xminI, xmaxI, yminI, ymaxI);
    scan5<<<B_, 1024, 0, stream>>>(counts, off);
    bounds5<<<2, 256, 0, stream>>>(counts, xminI, xmaxI, yminI, ymaxI,
                                   ylubA, yglbA, colxmin, colxmax);
    colpre<<<1, 64, 0, stream>>>(colxmin, colxmax, colxlub, colxglb);
    scatter5<<<N_ / 256, 256, 0, stream>>>(vc, off, cursors, pos4s);
    knn6_kernel<<<N_ / 4, 256, 0, stream>>>(pos4s, off, ylubA, yglbA,
                                            colxlub, colxglb, idx, d2);

    edge_kernel<4,32,true ><<<1024, 256, 0, stream>>>(pillar, idx, d2, W0, b0, wk0, wq0,
                                                      nullptr, nullptr, s0, sq0, nullptr, 8);
    finalize_kernel<<<1, 64, 0, stream>>>(s0, sq0, g0, be0, a0, c0, 32);
    edge_kernel<4,32,false><<<1024, 256, 0, stream>>>(pillar, idx, d2, W0, b0, wk0, wq0,
                                                      a0, c0, nullptr, nullptr, x1, 8);

    edge_kernel<32,64,true ><<<2048, 256, 0, stream>>>(x1, idx, d2, W1, b1, wk1, wq1,
                                                       nullptr, nullptr, s1, sq1, nullptr, 8);
    finalize_kernel<<<1, 64, 0, stream>>>(s1, sq1, g1, be1, a1, c1, 64);
    edge_kernel<32,64,false><<<2048, 256, 0, stream>>>(x1, idx, d2, W1, b1, wk1, wq1,
                                                       a1, c1, nullptr, nullptr, xout, 8);

    copy_vc<<<256, 256, 0, stream>>>((const float4*)vc, (float4*)vout);
}

// Round 9
// 1029.673 us; speedup vs baseline: 4.7336x; 4.7336x over previous
//
#include <hip/hip_runtime.h>
#include <math.h>

#define B_ 8
#define P_ 8192
#define N_ 65536
#define K_ 16
#define EPS_ 1e-5f
#define NBK 1024                 // x-buckets per batch
#define BSCALE 20.48f            // NBK / 50.0

typedef unsigned long long ull;

// ============================ 1D binning (R5, proven) ======================
__global__ __launch_bounds__(256) void init_bins(int* counts, int* cursors,
                                                 int* xminI, int* xmaxI) {
    int i = blockIdx.x * 256 + threadIdx.x;   // 8192 entries
    counts[i] = 0; cursors[i] = 0;
    xminI[i] = 0x7F7FFFFF;                    // non-neg floats: int order == float order
    xmaxI[i] = 0x80000000;
}

__device__ __forceinline__ int bucket_of(float x) {
    int b = (int)(x * BSCALE);
    return b > (NBK - 1) ? (NBK - 1) : (b < 0 ? 0 : b);
}

__global__ __launch_bounds__(256) void count_kernel(const float* __restrict__ vc,
                                                    int* counts, int* xminI, int* xmaxI) {
    int q = blockIdx.x * 256 + threadIdx.x;
    float4 p = ((const float4*)vc)[q];        // [batch, x, y, z]
    int b = q >> 13;
    int bk = bucket_of(p.y);
    int e = b * NBK + bk;
    atomicAdd(&counts[e], 1);
    int xb = __float_as_int(p.y);
    atomicMin(&xminI[e], xb);
    atomicMax(&xmaxI[e], xb);
}

__global__ __launch_bounds__(1024) void scan_kernel(const int* __restrict__ counts,
                                                    const int* __restrict__ xminI,
                                                    const int* __restrict__ xmaxI,
                                                    int* off, float* xlub, float* xglb) {
    __shared__ int   smi[NBK];
    __shared__ float smf[NBK];
    int b = blockIdx.x, t = threadIdx.x;
    int e = b * NBK + t;

    int c = counts[e];
    smi[t] = c; __syncthreads();
    for (int s = 1; s < NBK; s <<= 1) {
        int u = smi[t]; int v = (t >= s) ? smi[t - s] : 0;
        __syncthreads(); smi[t] = u + v; __syncthreads();
    }
    off[b * (NBK + 1) + t] = smi[t] - c;
    if (t == NBK - 1) off[b * (NBK + 1) + NBK] = smi[t];

    float mx = c ? __int_as_float(xmaxI[e]) : -1e30f;
    smf[t] = mx; __syncthreads();
    for (int s = 1; s < NBK; s <<= 1) {
        float u = smf[t]; float v = (t >= s) ? smf[t - s] : -1e30f;
        __syncthreads(); smf[t] = fmaxf(u, v); __syncthreads();
    }
    xlub[e] = smf[t];
    __syncthreads();

    int r = NBK - 1 - t;
    int cr_ = counts[b * NBK + r];
    float mn = cr_ ? __int_as_float(xminI[b * NBK + r]) : 1e30f;
    smf[t] = mn; __syncthreads();
    for (int s = 1; s < NBK; s <<= 1) {
        float u = smf[t]; float v = (t >= s) ? smf[t - s] : 1e30f;
        __syncthreads(); smf[t] = fminf(u, v); __syncthreads();
    }
    xglb[b * NBK + r] = smf[t];
}

__global__ __launch_bounds__(256) void scatter_kernel(const float* __restrict__ vc,
                                                      const int* __restrict__ off,
                                                      int* cursors, float4* pos4s) {
    int q = blockIdx.x * 256 + threadIdx.x;
    float4 p = ((const float4*)vc)[q];
    int b = q >> 13;
    int bk = bucket_of(p.y);
    int slot = off[b * (NBK + 1) + bk] + atomicAdd(&cursors[b * NBK + bk], 1);
    pos4s[(b << 13) + slot] = make_float4(p.y, p.z, p.w, __int_as_float(q));
}

// ============================ knn8: single-pass u64 network ================
// Block = 128 consecutive x-sorted queries, 2 threads/query (sub = tile slot
// parity). Tiles of <=256 candidates staged cooperatively into LDS; every
// thread runs a branchless sorted-insert network over u64 keys
// (d_bits<<32 | idx): u64 order == lex (d, idx) order == top_k semantics
// (incl. lowest-index ties). Single pass: the network IS the exact result.
// Window stop is non-strict (<= tau) and conservative under _rn monotonicity.
// End: pair merge via one more network pass over partner's sorted 16.
// All loops clamped/guarded -> bounded even with poisoned workspace.
__global__ __launch_bounds__(256) void knn8_kernel(const float4* __restrict__ pos4s,
                                                   const float* __restrict__ xlub,
                                                   const float* __restrict__ xglb,
                                                   unsigned short* __restrict__ idx_out,
                                                   float* __restrict__ d2_out) {
    const int tid = threadIdx.x;
    const int sub = tid >> 7;                 // tile-slot parity
    const int qi  = tid & 127;                // query within block
    const int bb  = blockIdx.x >> 6;          // batch (64 blocks/batch)
    const int bbase = bb << 13;
    const int home0 = bbase + ((blockIdx.x & 63) << 7);
    const float4 me = pos4s[home0 + qi];
    const float qx = me.x, qy = me.y, qz = me.z;
    const int q = __float_as_int(me.w);
    const float* xl = xlub + (bb << 10);
    const float* xg = xglb + (bb << 10);

    __shared__ __align__(16) float4 tile[256];  // 4 KB
    __shared__ ull pk[128][K_];                 // 16 KB partner dump
    __shared__ int sflags[2];

    ull kb[K_];
#pragma unroll
    for (int t = 0; t < K_; ++t) kb[t] = ~0ull;

#define PROC8(c_) {                                                         \
        float dx_ = __fsub_rn(qx, (c_).x);                                  \
        float dy_ = __fsub_rn(qy, (c_).y);                                  \
        float dz_ = __fsub_rn(qz, (c_).z);                                  \
        float d_  = __fadd_rn(__fadd_rn(__fmul_rn(dx_,dx_),                 \
                                        __fmul_rn(dy_,dy_)),                \
                              __fmul_rn(dz_,dz_));                          \
        ull key_ = ((ull)(unsigned)__float_as_int(d_) << 32)                \
                 | (unsigned)__float_as_int((c_).w);                        \
        if (key_ < kb[K_-1]) {                                              \
            _Pragma("unroll")                                               \
            for (int t = K_-1; t > 0; --t) {                                \
                ull hi_ = kb[t-1] > key_ ? kb[t-1] : key_;                  \
                kb[t] = kb[t] < hi_ ? kb[t] : hi_;                          \
            }                                                               \
            kb[0] = kb[0] < key_ ? kb[0] : key_;                            \
        }                                                                   \
    }

#define SCAN8(base, cnt) {                                                  \
        __syncthreads();                                                    \
        for (int i = tid; i < (cnt); i += 256) tile[i] = pos4s[(base) + i]; \
        __syncthreads();                                                    \
        _Pragma("unroll 2")                                                 \
        for (int j = sub; j < (cnt); j += 2) { float4 c_ = tile[j]; PROC8(c_) } \
    }

    // ---- home tile (128 candidates; each thread sees 64 >= 16) ----
    SCAN8(home0, 128)
    int sL = home0, sR = home0 + 128;
    float tau = __uint_as_float((unsigned)(kb[K_-1] >> 32));

    for (int guard = 0; guard < 80; ++guard) {
        bool needL = false, needR = false;
        if (sL > bbase) {
            float xb = xl[bucket_of(pos4s[sL - 1].x)];   // ub on x of slots < sL
            float t = __fsub_rn(qx, xb);
            needL = __fmul_rn(t, t) <= tau;              // non-strict: tie-safe
        }
        if (sR < bbase + P_) {
            float xb = xg[bucket_of(pos4s[sR].x)];       // lb on x of slots >= sR
            float t = __fsub_rn(xb, qx);
            needR = __fmul_rn(t, t) <= tau;
        }
        if (tid == 0) { sflags[0] = 0; sflags[1] = 0; }
        __syncthreads();
        if (needL) sflags[0] = 1;
        if (needR) sflags[1] = 1;
        __syncthreads();
        int aL = sflags[0], aR = sflags[1];
        if (!aL && !aR) break;
        if (aL) { int c_ = min(256, sL - bbase);       SCAN8(sL - c_, c_) sL -= c_; }
        if (aR) { int c_ = min(256, bbase + P_ - sR);  SCAN8(sR, c_)      sR += c_; }
        tau = __uint_as_float((unsigned)(kb[K_-1] >> 32));
    }

    // ---- pair merge: partner's sorted 16 through the same network ----
    __syncthreads();
    if (sub) {
#pragma unroll
        for (int t = 0; t < K_; ++t) pk[qi][t] = kb[t];
    }
    __syncthreads();
    if (!sub) {
#pragma unroll
        for (int t = 0; t < K_; ++t) {
            ull key_ = pk[qi][t];
            if (key_ >= kb[K_-1]) break;   // partner list sorted: rest are bigger
#pragma unroll
            for (int u = K_-1; u > 0; --u) {
                ull hi_ = kb[u-1] > key_ ? kb[u-1] : key_;
                kb[u] = kb[u] < hi_ ? kb[u] : hi_;
            }
            kb[0] = kb[0] < key_ ? kb[0] : key_;
        }
#pragma unroll
        for (int t = 0; t < K_; ++t) {
            idx_out[(size_t)q * K_ + t] = (unsigned short)(kb[t] & 0xffffu);
            d2_out[(size_t)q * K_ + t]  = __uint_as_float((unsigned)(kb[t] >> 32));
        }
    }
#undef PROC8
#undef SCAN8
}

// ============================ edgeconv (unchanged) =========================
static __device__ inline double shfl_xor_dbl(double v, int mask) {
    long long b = __double_as_longlong(v);
    int lo = (int)(b & 0xffffffffLL);
    int hi = (int)(b >> 32);
    lo = __shfl_xor(lo, mask, 64);
    hi = __shfl_xor(hi, mask, 64);
    return __longlong_as_double(((long long)hi << 32) | (unsigned long long)(unsigned int)lo);
}

template<int CIN, int COUT, bool PHA>
__global__ __launch_bounds__(256) void edge_kernel(
    const float* __restrict__ x,
    const unsigned short* __restrict__ idx,
    const float* __restrict__ d2,
    const float* __restrict__ W,
    const float* __restrict__ bias,
    const float* __restrict__ wk,
    const float* __restrict__ wq,
    const float* __restrict__ acoef,
    const float* __restrict__ ccoef,
    double* __restrict__ gsum,
    double* __restrict__ gsumsq,
    float* __restrict__ out,
    int niter)
{
    constexpr int LOGC = (COUT == 64) ? 6 : 5;
    constexpr int GPW  = 64 / COUT;
    constexpr int GPB  = 4 * GPW;
    constexpr int C4   = CIN / 4;
    constexpr int SJ   = (K_ + 1) * CIN;
    constexpr int HTS  = COUT + 1;
    constexpr int HTN  = PHA ? 1 : (K_ * HTS);
    constexpr int PN   = PHA ? 1 : (K_ * K_);
    constexpr int KQN  = PHA ? 1 : (2 * K_);
    constexpr int SCN  = PHA ? 1 : K_;
    constexpr int PARTN= (!PHA && COUT == 64) ? 64 : 1;
    constexpr int WKQN = PHA ? 1 : (2 * COUT);

    const int tid  = threadIdx.x;
    const int wave = tid >> 6;
    const int lane = tid & 63;
    const int lo   = lane & (COUT - 1);
    const int grp  = lane >> LOGC;
    const int gidx = wave * GPW + grp;

    __shared__ __align__(16) float sj_s[GPB][SJ];
    __shared__ __align__(16) float hT_s[GPB][HTN];
    __shared__ __align__(16) float p_s[GPB][PN];
    __shared__ __align__(16) float kqv_s[GPB][KQN];
    __shared__ __align__(16) float rden_s[GPB][SCN];
    __shared__ __align__(16) float scal_s[GPB][SCN];
    __shared__ __align__(16) float part_s[GPB][PARTN];
    __shared__ __align__(16) float wkq_s[WKQN];

    float Wr[CIN], Ad[CIN];
#pragma unroll
    for (int c = 0; c < CIN; ++c) {
        float wl = W[lo * (2*CIN) + c];
        float wr = W[lo * (2*CIN) + CIN + c];
        Wr[c] = wr; Ad[c] = wl - wr;
    }
    const float b_s = bias[lo];

    float a_s = 0.f, c_s = 0.f;
    if constexpr (!PHA) {
        a_s = acoef[lo]; c_s = ccoef[lo];
        if (tid < COUT)            wkq_s[tid] = wk[tid];
        else if (tid < 2*COUT)     wkq_s[tid] = wq[tid - COUT];
    }
    __syncthreads();

    double lsum = 0.0, lsq = 0.0;
    const int g0      = blockIdx.x * GPB + gidx;
    const int gstride = gridDim.x * GPB;

    for (int it = 0; it < niter; ++it) {
        const int n = g0 + it * gstride;

        {
            const float4* xs  = (const float4*)x;
            float4*       sj4 = (float4*)sj_s[gidx];
            constexpr int TOT4 = (K_ + 1) * C4;
#pragma unroll
            for (int e0 = 0; e0 < TOT4; e0 += COUT) {
                int e = e0 + lo;
                if (e < TOT4) {
                    int r = e / C4;
                    int c = e - r * C4;
                    int row = (r < K_) ? (int)idx[n * K_ + r] : n;
                    sj4[e] = xs[row * C4 + c];
                }
            }
        }
        if constexpr (!PHA) {
            if (lo < K_) {
                float dis = sqrtf(d2[n * K_ + lo]);
                float e = __expf(-dis);
                scal_s[gidx][lo] = 2.0f * e / (1.0f + e);
            }
        }
        __syncthreads();

        const float* sj = sj_s[gidx];
        float t0 = b_s;
#pragma unroll
        for (int c = 0; c < C4; ++c) {
            float4 v = ((const float4*)(sj + K_ * CIN))[c];
            t0 = fmaf(Ad[4*c  ], v.x, t0);
            t0 = fmaf(Ad[4*c+1], v.y, t0);
            t0 = fmaf(Ad[4*c+2], v.z, t0);
            t0 = fmaf(Ad[4*c+3], v.w, t0);
        }
        float hn[K_];
#pragma unroll
        for (int k = 0; k < K_; ++k) {
            float acc = t0;
            const float4* xr = (const float4*)(sj + k * CIN);
#pragma unroll
            for (int c = 0; c < C4; ++c) {
                float4 v = xr[c];
                acc = fmaf(Wr[4*c  ], v.x, acc);
                acc = fmaf(Wr[4*c+1], v.y, acc);
                acc = fmaf(Wr[4*c+2], v.z, acc);
                acc = fmaf(Wr[4*c+3], v.w, acc);
            }
            float h = fmaxf(acc, 0.f);
            if constexpr (PHA) {
                double hd = (double)h;
                lsum += hd;
                lsq  = fma(hd, hd, lsq);
            } else {
                hn[k] = fmaf(a_s, h, c_s);
            }
        }

        if constexpr (!PHA) {
            float* hT = hT_s[gidx];
#pragma unroll
            for (int k = 0; k < K_; ++k) hT[k * HTS + lo] = hn[k];
            __syncthreads();

            const int kk   = lo & 15;
            const int role = lo >> 4;
            float av = 0.f;
            const float* hrow = hT + kk * HTS;
            int obase; const float* wv;
            if constexpr (COUT == 64) { obase = (role & 1) * 32; wv = wkq_s + ((role >> 1) ? COUT : 0); }
            else                      { obase = 0;               wv = wkq_s + (role ? COUT : 0); }
#pragma unroll
            for (int j = 0; j < 32; ++j)
                av = fmaf(hrow[obase + j], wv[obase + j], av);
            if constexpr (COUT == 64) {
                part_s[gidx][lo] = av;
                __syncthreads();
                if (lo < 16)      kqv_s[gidx][lo] = part_s[gidx][lo]      + part_s[gidx][lo + 16];
                else if (lo < 32) kqv_s[gidx][lo] = part_s[gidx][lo + 16] + part_s[gidx][lo + 32];
            } else {
                kqv_s[gidx][lo] = av;
            }
            __syncthreads();

            if (lo < K_) {
                const int qq = lo;
                const float qv = kqv_s[gidx][K_ + qq];
                float m = -__builtin_huge_valf();
#pragma unroll
                for (int k = 0; k < K_; ++k) m = fmaxf(m, kqv_s[gidx][k] * qv);
                float den = 0.f;
#pragma unroll
                for (int k = 0; k < K_; ++k) {
                    float e = __expf(kqv_s[gidx][k] * qv - m);
                    den += e;
                    p_s[gidx][k * K_ + qq] = e;
                }
                rden_s[gidx][qq] = 1.0f / den;
            }
            __syncthreads();

            float hq[K_];
#pragma unroll
            for (int qq = 0; qq < K_; ++qq) hq[qq] = 0.f;
#pragma unroll
            for (int k = 0; k < K_; ++k) {
                const float hnk = hn[k];
                const float4* p4 = (const float4*)(p_s[gidx] + k * K_);
#pragma unroll
                for (int j = 0; j < 4; ++j) {
                    float4 v = p4[j];
                    hq[4*j  ] = fmaf(hnk, v.x, hq[4*j  ]);
                    hq[4*j+1] = fmaf(hnk, v.y, hq[4*j+1]);
                    hq[4*j+2] = fmaf(hnk, v.z, hq[4*j+2]);
                    hq[4*j+3] = fmaf(hnk, v.w, hq[4*j+3]);
                }
            }
            float res = -__builtin_huge_valf();
#pragma unroll
            for (int j = 0; j < 4; ++j) {
                float4 sc = ((const float4*)scal_s[gidx])[j];
                float4 rd = ((const float4*)rden_s[gidx])[j];
                res = fmaxf(res, sc.x * (hq[4*j  ] * rd.x));
                res = fmaxf(res, sc.y * (hq[4*j+1] * rd.y));
                res = fmaxf(res, sc.z * (hq[4*j+2] * rd.z));
                res = fmaxf(res, sc.w * (hq[4*j+3] * rd.w));
            }
            out[n * COUT + lo] = res;
            __syncthreads();
        } else {
            __syncthreads();
        }
    }

    if constexpr (PHA) {
        if constexpr (COUT == 32) {
            lsum += shfl_xor_dbl(lsum, 32);
            lsq  += shfl_xor_dbl(lsq, 32);
        }
        __shared__ double redS[4][COUT];
        __shared__ double redQ[4][COUT];
        if (lane < COUT) { redS[wave][lane] = lsum; redQ[wave][lane] = lsq; }
        __syncthreads();
        if (tid < COUT) {
            double ss = redS[0][tid] + redS[1][tid] + redS[2][tid] + redS[3][tid];
            double qq = redQ[0][tid] + redQ[1][tid] + redQ[2][tid] + redQ[3][tid];
            atomicAdd(&gsum[tid], ss);
            atomicAdd(&gsumsq[tid], qq);
        }
    }
}

__global__ void finalize_kernel(const double* __restrict__ gsum, const double* __restrict__ gsumsq,
                                const float* __restrict__ gamma, const float* __restrict__ beta,
                                float* __restrict__ a, float* __restrict__ c, int cout)
{
    int o = threadIdx.x;
    if (o < cout) {
        const double inv = 1.0 / ((double)N_ * (double)K_);
        double mu  = gsum[o] * inv;
        double var = gsumsq[o] * inv - mu * mu;
        double rs  = 1.0 / sqrt(var + (double)EPS_);
        double av  = rs * (double)gamma[o];
        a[o] = (float)av;
        c[o] = (float)((double)beta[o] - mu * av);
    }
}

__global__ __launch_bounds__(256) void copy_vc(const float4* __restrict__ src,
                                               float4* __restrict__ dst) {
    int i = blockIdx.x * 256 + threadIdx.x;
    dst[i] = src[i];
}

extern "C" void kernel_launch(void* const* d_in, const int* in_sizes, int n_in,
                              void* d_out, int out_size, void* d_ws, size_t ws_size,
                              hipStream_t stream)
{
    const float* pillar = (const float*)d_in[0];
    const float* vc     = (const float*)d_in[1];
    const float* W0  = (const float*)d_in[2];
    const float* b0  = (const float*)d_in[3];
    const float* g0  = (const float*)d_in[4];
    const float* be0 = (const float*)d_in[5];
    const float* wk0 = (const float*)d_in[6];
    const float* wq0 = (const float*)d_in[7];
    const float* W1  = (const float*)d_in[8];
    const float* b1  = (const float*)d_in[9];
    const float* g1  = (const float*)d_in[10];
    const float* be1 = (const float*)d_in[11];
    const float* wk1 = (const float*)d_in[12];
    const float* wq1 = (const float*)d_in[13];

    // ---- workspace (< 16 MiB total) ----
    char* ws = (char*)d_ws;
    double* dsum = (double*)ws;                              // 2 KB @ 0
    double *s0 = dsum, *sq0 = dsum + 64, *s1 = dsum + 128, *sq1 = dsum + 192;
    float* coef = (float*)(ws + 4096);                       // 1 KB @ 4K
    float *a0 = coef, *c0 = coef + 64, *a1 = coef + 128, *c1 = coef + 192;
    unsigned short* idx = (unsigned short*)(ws + 8192);      // 2 MB
    float* d2  = (float*)(ws + 8192 + (size_t)N_*K_*2);      // 4 MB
    float* x1  = (float*)(ws + 8192 + (size_t)N_*K_*6);      // 8 MB
    size_t base2 = 8192 + (size_t)N_*K_*6 + (size_t)N_*32*4; // = 14 MB + 8 KB
    float4* pos4s = (float4*)(ws + base2);                   // 1 MB
    int* counts   = (int*)(ws + base2 + (1u<<20));           // 32 KB
    int* cursors  = counts + B_*NBK;                         // 32 KB
    int* off      = cursors + B_*NBK;                        // 8*1025*4
    int* xminI    = off + B_*(NBK+1);                        // 32 KB
    int* xmaxI    = xminI + B_*NBK;                          // 32 KB
    float* xlub   = (float*)(xmaxI + B_*NBK);                // 32 KB
    float* xglb   = xlub + B_*NBK;                           // 32 KB

    float* xout = (float*)d_out;
    float* vout = xout + (size_t)N_ * 64;

    hipMemsetAsync(dsum, 0, 2048, stream);
    init_bins<<<B_*NBK/256, 256, 0, stream>>>(counts, cursors, xminI, xmaxI);
    count_kernel<<<N_/256, 256, 0, stream>>>(vc, counts, xminI, xmaxI);
    scan_kernel<<<B_, NBK, 0, stream>>>(counts, xminI, xmaxI, off, xlub, xglb);
    scatter_kernel<<<N_/256, 256, 0, stream>>>(vc, off, cursors, pos4s);
    knn8_kernel<<<N_/128, 256, 0, stream>>>(pos4s, xlub, xglb, idx, d2);

    edge_kernel<4,32,true ><<<1024, 256, 0, stream>>>(pillar, idx, d2, W0, b0, wk0, wq0,
                                                      nullptr, nullptr, s0, sq0, nullptr, 8);
    finalize_kernel<<<1, 64, 0, stream>>>(s0, sq0, g0, be0, a0, c0, 32);
    edge_kernel<4,32,false><<<1024, 256, 0, stream>>>(pillar, idx, d2, W0, b0, wk0, wq0,
                                                      a0, c0, nullptr, nullptr, x1, 8);

    edge_kernel<32,64,true ><<<2048, 256, 0, stream>>>(x1, idx, d2, W1, b1, wk1, wq1,
                                                       nullptr, nullptr, s1, sq1, nullptr, 8);
    finalize_kernel<<<1, 64, 0, stream>>>(s1, sq1, g1, be1, a1, c1, 64);
    edge_kernel<32,64,false><<<2048, 256, 0, stream>>>(x1, idx, d2, W1, b1, wk1, wq1,
                                                       a1, c1, nullptr, nullptr, xout, 8);

    copy_vc<<<256, 256, 0, stream>>>((const float4*)vc, (float4*)vout);
}

// Round 10
// 946.307 us; speedup vs baseline: 5.1506x; 1.0881x over previous
//
#include <hip/hip_runtime.h>
#include <math.h>

#define B_ 8
#define P_ 8192
#define N_ 65536
#define K_ 16
#define EPS_ 1e-5f
#define NBK 1024                 // x-buckets per batch
#define BSCALE 20.48f            // NBK / 50.0

// ============================ binning (R5, proven) =========================
__global__ __launch_bounds__(256) void init_bins(int* counts, int* cursors,
                                                 int* xminI, int* xmaxI) {
    int i = blockIdx.x * 256 + threadIdx.x;   // 8192 entries
    counts[i] = 0; cursors[i] = 0;
    xminI[i] = 0x7F7FFFFF;                    // non-neg floats: int order == float order
    xmaxI[i] = 0x80000000;
}

__device__ __forceinline__ int bucket_of(float x) {
    int b = (int)(x * BSCALE);
    return b > (NBK - 1) ? (NBK - 1) : (b < 0 ? 0 : b);
}

__global__ __launch_bounds__(256) void count_kernel(const float* __restrict__ vc,
                                                    int* counts, int* xminI, int* xmaxI) {
    int q = blockIdx.x * 256 + threadIdx.x;
    float4 p = ((const float4*)vc)[q];        // [batch, x, y, z]
    int b = q >> 13;
    int bk = bucket_of(p.y);
    int e = b * NBK + bk;
    atomicAdd(&counts[e], 1);
    int xb = __float_as_int(p.y);
    atomicMin(&xminI[e], xb);
    atomicMax(&xmaxI[e], xb);
}

__global__ __launch_bounds__(1024) void scan_kernel(const int* __restrict__ counts,
                                                    const int* __restrict__ xminI,
                                                    const int* __restrict__ xmaxI,
                                                    int* off, float* xlub, float* xglb) {
    __shared__ int   smi[NBK];
    __shared__ float smf[NBK];
    int b = blockIdx.x, t = threadIdx.x;
    int e = b * NBK + t;

    int c = counts[e];
    smi[t] = c; __syncthreads();
    for (int s = 1; s < NBK; s <<= 1) {
        int u = smi[t]; int v = (t >= s) ? smi[t - s] : 0;
        __syncthreads(); smi[t] = u + v; __syncthreads();
    }
    off[b * (NBK + 1) + t] = smi[t] - c;
    if (t == NBK - 1) off[b * (NBK + 1) + NBK] = smi[t];

    float mx = c ? __int_as_float(xmaxI[e]) : -1e30f;
    smf[t] = mx; __syncthreads();
    for (int s = 1; s < NBK; s <<= 1) {
        float u = smf[t]; float v = (t >= s) ? smf[t - s] : -1e30f;
        __syncthreads(); smf[t] = fmaxf(u, v); __syncthreads();
    }
    xlub[e] = smf[t];
    __syncthreads();

    int r = NBK - 1 - t;
    int cr_ = counts[b * NBK + r];
    float mn = cr_ ? __int_as_float(xminI[b * NBK + r]) : 1e30f;
    smf[t] = mn; __syncthreads();
    for (int s = 1; s < NBK; s <<= 1) {
        float u = smf[t]; float v = (t >= s) ? smf[t - s] : 1e30f;
        __syncthreads(); smf[t] = fminf(u, v); __syncthreads();
    }
    xglb[b * NBK + r] = smf[t];
}

__global__ __launch_bounds__(256) void scatter_kernel(const float* __restrict__ vc,
                                                      const int* __restrict__ off,
                                                      int* cursors, float4* pos4s) {
    int q = blockIdx.x * 256 + threadIdx.x;
    float4 p = ((const float4*)vc)[q];
    int b = q >> 13;
    int bk = bucket_of(p.y);
    int slot = off[b * (NBK + 1) + bk] + atomicAdd(&cursors[b * NBK + bk], 1);
    pos4s[(b << 13) + slot] = make_float4(p.y, p.z, p.w, __int_as_float(q));
}

// ============================ knn3 (R5, proven 510 us) =====================
__global__ __launch_bounds__(256) void knn3_kernel(const float4* __restrict__ pos4s,
                                                   const float* __restrict__ xlub,
                                                   const float* __restrict__ xglb,
                                                   unsigned short* __restrict__ idx_out,
                                                   float* __restrict__ d2_out) {
    const int tid   = threadIdx.x;
    const int bb    = blockIdx.x >> 5;            // batch (32 blocks/batch)
    const int bbase = bb << 13;
    const int home0 = bbase + ((blockIdx.x & 31) << 8);
    const float4 me = pos4s[home0 + tid];
    const float qx = me.x, qy = me.y, qz = me.z;
    const int q = __float_as_int(me.w);
    const float* xl = xlub + (bb << 10);
    const float* xg = xglb + (bb << 10);

    __shared__ __align__(16) float4 tile[256];    // 4 KB
    __shared__ float2 hb[256 * 19];               // 38 KB hit buffer
    __shared__ int sflags[2];

    float bd[K_];
#pragma unroll
    for (int t = 0; t < K_; ++t) bd[t] = __builtin_huge_valf();
    float bd15 = __builtin_huge_valf();

#define DIST_(c)                                                            \
    float dx = __fsub_rn(qx, (c).x);                                        \
    float dy = __fsub_rn(qy, (c).y);                                        \
    float dz = __fsub_rn(qz, (c).z);                                        \
    float d  = __fadd_rn(__fadd_rn(__fmul_rn(dx,dx), __fmul_rn(dy,dy)),     \
                         __fmul_rn(dz,dz));

#define SCAN_P1(base, cntT) {                                               \
    __syncthreads();                                                        \
    if (tid < (cntT)) tile[tid] = pos4s[(base) + tid];                      \
    __syncthreads();                                                        \
    _Pragma("unroll 4")                                                     \
    for (int j = 0; j < (cntT); ++j) {                                      \
        float4 c = tile[j];                                                 \
        DIST_(c)                                                            \
        if (d < bd15) {                                                     \
            _Pragma("unroll")                                               \
            for (int t = K_-1; t > 0; --t)                                  \
                bd[t] = fminf(bd[t], fmaxf(bd[t-1], d));                    \
            bd[0] = fminf(bd[0], d);                                        \
            bd15 = bd[K_-1];                                                \
        }                                                                   \
    } }

    // ---- pass 1: home tile, then center-outward expansion ----
    SCAN_P1(home0, 256)
    int sL = home0, sR = home0 + 256;
    for (;;) {
        bool needL = false, needR = false;
        if (sL > bbase) {
            float xb = xl[bucket_of(pos4s[sL - 1].x)];   // ub on x of slots < sL
            float t = __fsub_rn(qx, xb);
            needL = __fmul_rn(t, t) < bd15;
        }
        if (sR < bbase + P_) {
            float xb = xg[bucket_of(pos4s[sR].x)];       // lb on x of slots >= sR
            float t = __fsub_rn(xb, qx);
            needR = __fmul_rn(t, t) < bd15;
        }
        if (tid == 0) { sflags[0] = 0; sflags[1] = 0; }
        __syncthreads();
        if (needL) sflags[0] = 1;
        if (needR) sflags[1] = 1;
        __syncthreads();
        int aL = sflags[0], aR = sflags[1];
        if (!aL && !aR) break;
        if (aL) { int c_ = min(256, sL - bbase);       SCAN_P1(sL - c_, c_) sL -= c_; }
        if (aR) { int c_ = min(256, bbase + P_ - sR);  SCAN_P1(sR, c_)      sR += c_; }
    }

    // ---- pass 2: collect (d, idx) with d <= tau ----
    const float tau = bd15;
    int cnt = 0;
    const int hbase = tid * 19;

#define SCAN_P2(base, cntT) {                                               \
    __syncthreads();                                                        \
    if (tid < (cntT)) tile[tid] = pos4s[(base) + tid];                      \
    __syncthreads();                                                        \
    _Pragma("unroll 4")                                                     \
    for (int j = 0; j < (cntT); ++j) {                                      \
        float4 c = tile[j];                                                 \
        DIST_(c)                                                            \
        if (d <= tau && cnt < 19) {                                         \
            hb[hbase + cnt] = make_float2(d, c.w);                          \
            ++cnt;                                                          \
        }                                                                   \
    } }

    SCAN_P2(home0, 256)
    sL = home0; sR = home0 + 256;
    for (;;) {
        bool needL = false, needR = false;
        if (sL > bbase) {
            float xb = xl[bucket_of(pos4s[sL - 1].x)];
            float t = __fsub_rn(qx, xb);
            needL = __fmul_rn(t, t) <= tau;
        }
        if (sR < bbase + P_) {
            float xb = xg[bucket_of(pos4s[sR].x)];
            float t = __fsub_rn(xb, qx);
            needR = __fmul_rn(t, t) <= tau;
        }
        if (tid == 0) { sflags[0] = 0; sflags[1] = 0; }
        __syncthreads();
        if (needL) sflags[0] = 1;
        if (needR) sflags[1] = 1;
        __syncthreads();
        int aL = sflags[0], aR = sflags[1];
        if (!aL && !aR) break;
        if (aL) { int c_ = min(256, sL - bbase);       SCAN_P2(sL - c_, c_) sL -= c_; }
        if (aR) { int c_ = min(256, bbase + P_ - sR);  SCAN_P2(sR, c_)      sR += c_; }
    }

    // ---- readback + drop lex-largest extras (ties; cnt>16 is rare) ----
    float dc[19]; int ic[19];
#pragma unroll
    for (int t = 0; t < 19; ++t) {
        float2 v = hb[hbase + t];
        dc[t] = v.x; ic[t] = __float_as_int(v.y);
    }
    while (cnt > 16) {
        float md = dc[0]; int mi = ic[0]; int mt = 0;
#pragma unroll
        for (int t = 1; t < 19; ++t) {
            bool valid = (t < cnt);
            bool g = valid && ((dc[t] > md) || (dc[t] == md && ic[t] > mi));
            if (g) { md = dc[t]; mi = ic[t]; mt = t; }
        }
        float ld = 0.f; int li = 0;
#pragma unroll
        for (int t = 0; t < 19; ++t) if (t == cnt - 1) { ld = dc[t]; li = ic[t]; }
#pragma unroll
        for (int t = 0; t < 19; ++t) if (t == mt) { dc[t] = ld; ic[t] = li; }
        --cnt;
    }

#pragma unroll
    for (int t = 0; t < K_; ++t) {
        idx_out[(size_t)q * K_ + t] = (unsigned short)ic[t];
        d2_out[(size_t)q * K_ + t]  = dc[t];
    }
#undef SCAN_P1
#undef SCAN_P2
#undef DIST_
}

// ============================ edgeconv (barrier-free) ======================
// A group (the COUT lanes handling one point) lives entirely inside ONE wave
// (COUT=64: group == wave; COUT=32: half-wave). All LDS producer->consumer
// handoffs are wave-internal: per-wave LDS program order + compiler lgkmcnt
// waits make them correct with only __builtin_amdgcn_wave_barrier() (a
// zero-cost compiler fence) -- no s_barrier in the whole main loop.
// COUT=64 Kv/Qv partials combine via shfl_xor(16) (no LDS round-trip).
// Phase A: f32 per-point partial sums (16 bounded terms), folded to f64 once
// per point (f64 cancellation safety across the 1M-sample reduction).
template<int CIN, int COUT, bool PHA>
__global__ __launch_bounds__(256) void edge_kernel(
    const float* __restrict__ x,
    const unsigned short* __restrict__ idx,
    const float* __restrict__ d2,
    const float* __restrict__ W,
    const float* __restrict__ bias,
    const float* __restrict__ wk,
    const float* __restrict__ wq,
    const float* __restrict__ acoef,
    const float* __restrict__ ccoef,
    double* __restrict__ gsum,
    double* __restrict__ gsumsq,
    float* __restrict__ out,
    int niter)
{
    constexpr int LOGC = (COUT == 64) ? 6 : 5;
    constexpr int GPW  = 64 / COUT;
    constexpr int GPB  = 4 * GPW;
    constexpr int C4   = CIN / 4;
    constexpr int SJ   = (K_ + 1) * CIN;
    constexpr int HTS  = COUT + 1;
    constexpr int HTN  = PHA ? 1 : (K_ * HTS);
    constexpr int PN   = PHA ? 1 : (K_ * K_);
    constexpr int KQN  = PHA ? 1 : (2 * K_);
    constexpr int SCN  = PHA ? 1 : K_;
    constexpr int WKQN = PHA ? 1 : (2 * COUT);

    const int tid  = threadIdx.x;
    const int wave = tid >> 6;
    const int lane = tid & 63;
    const int lo   = lane & (COUT - 1);
    const int grp  = lane >> LOGC;
    const int gidx = wave * GPW + grp;

    __shared__ __align__(16) float sj_s[GPB][SJ];
    __shared__ __align__(16) float hT_s[GPB][HTN];
    __shared__ __align__(16) float p_s[GPB][PN];
    __shared__ __align__(16) float kqv_s[GPB][KQN];
    __shared__ __align__(16) float rden_s[GPB][SCN];
    __shared__ __align__(16) float scal_s[GPB][SCN];
    __shared__ __align__(16) float wkq_s[WKQN];

    float Wr[CIN], Ad[CIN];
#pragma unroll
    for (int c = 0; c < CIN; ++c) {
        float wl = W[lo * (2*CIN) + c];
        float wr = W[lo * (2*CIN) + CIN + c];
        Wr[c] = wr; Ad[c] = wl - wr;
    }
    const float b_s = bias[lo];

    float a_s = 0.f, c_s = 0.f;
    if constexpr (!PHA) {
        a_s = acoef[lo]; c_s = ccoef[lo];
        if (tid < COUT)            wkq_s[tid] = wk[tid];
        else if (tid < 2*COUT)     wkq_s[tid] = wq[tid - COUT];
        __syncthreads();   // the ONLY block barrier (wkq_s is cross-wave)
    }

    double lsum = 0.0, lsq = 0.0;
    const int g0      = blockIdx.x * GPB + gidx;
    const int gstride = gridDim.x * GPB;

    for (int it = 0; it < niter; ++it) {
        const int n = g0 + it * gstride;

        // ---- stage xj rows (k<K) and xi row (k==K) into LDS (float4) ----
        {
            const float4* xs  = (const float4*)x;
            float4*       sj4 = (float4*)sj_s[gidx];
            constexpr int TOT4 = (K_ + 1) * C4;
#pragma unroll
            for (int e0 = 0; e0 < TOT4; e0 += COUT) {
                int e = e0 + lo;
                if (e < TOT4) {
                    int r = e / C4;
                    int c = e - r * C4;
                    int row = (r < K_) ? (int)idx[n * K_ + r] : n;
                    sj4[e] = xs[row * C4 + c];
                }
            }
        }
        if constexpr (!PHA) {
            if (lo < K_) {
                float dis = sqrtf(d2[n * K_ + lo]);
                float e = __expf(-dis);
                scal_s[gidx][lo] = 2.0f * e / (1.0f + e);
            }
        }
        __builtin_amdgcn_wave_barrier();   // staging -> compute (wave-internal)

        const float* sj = sj_s[gidx];
        float t0 = b_s;
#pragma unroll
        for (int c = 0; c < C4; ++c) {
            float4 v = ((const float4*)(sj + K_ * CIN))[c];
            t0 = fmaf(Ad[4*c  ], v.x, t0);
            t0 = fmaf(Ad[4*c+1], v.y, t0);
            t0 = fmaf(Ad[4*c+2], v.z, t0);
            t0 = fmaf(Ad[4*c+3], v.w, t0);
        }
        float hn[K_];
        float psum = 0.f, psq = 0.f;
#pragma unroll
        for (int k = 0; k < K_; ++k) {
            float acc = t0;
            const float4* xr = (const float4*)(sj + k * CIN);
#pragma unroll
            for (int c = 0; c < C4; ++c) {
                float4 v = xr[c];
                acc = fmaf(Wr[4*c  ], v.x, acc);
                acc = fmaf(Wr[4*c+1], v.y, acc);
                acc = fmaf(Wr[4*c+2], v.z, acc);
                acc = fmaf(Wr[4*c+3], v.w, acc);
            }
            float h = fmaxf(acc, 0.f);
            if constexpr (PHA) {
                psum += h; psq = fmaf(h, h, psq);
            } else {
                hn[k] = fmaf(a_s, h, c_s);
            }
        }
        if constexpr (PHA) {
            lsum += (double)psum;        // f64 only across points
            lsq  += (double)psq;
        }

        if constexpr (!PHA) {
            // transpose to LDS (padded stride -> conflict-free columns)
            float* hT = hT_s[gidx];
#pragma unroll
            for (int k = 0; k < K_; ++k) hT[k * HTS + lo] = hn[k];
            __builtin_amdgcn_wave_barrier();   // transpose -> Kv/Qv

            const int kk   = lo & 15;
            const int role = lo >> 4;
            float av = 0.f;
            const float* hrow = hT + kk * HTS;
            int obase; const float* wv;
            if constexpr (COUT == 64) { obase = (role & 1) * 32; wv = wkq_s + ((role >> 1) ? COUT : 0); }
            else                      { obase = 0;               wv = wkq_s + (role ? COUT : 0); }
#pragma unroll
            for (int j = 0; j < 32; ++j)
                av = fmaf(hrow[obase + j], wv[obase + j], av);
            if constexpr (COUT == 64) {
                // halves combine in-register: lanes {kk,kk+16}->Kv, {kk+32,kk+48}->Qv
                float sum2 = av + __shfl_xor(av, 16, 64);
                if (lo < 16)                  kqv_s[gidx][kk] = sum2;        // Kv
                else if (lo >= 32 && lo < 48) kqv_s[gidx][16 + kk] = sum2;   // Qv
            } else {
                kqv_s[gidx][lo] = av;   // [0,16)=Kv, [16,32)=Qv
            }
            __builtin_amdgcn_wave_barrier();   // kqv -> softmax

            if (lo < K_) {
                const int qq = lo;
                const float qv = kqv_s[gidx][K_ + qq];
                float m = -__builtin_huge_valf();
#pragma unroll
                for (int k = 0; k < K_; ++k) m = fmaxf(m, kqv_s[gidx][k] * qv);
                float den = 0.f;
#pragma unroll
                for (int k = 0; k < K_; ++k) {
                    float e = __expf(kqv_s[gidx][k] * qv - m);
                    den += e;
                    p_s[gidx][k * K_ + qq] = e;
                }
                rden_s[gidx][qq] = 1.0f / den;
            }
            __builtin_amdgcn_wave_barrier();   // softmax -> weighted sum

            float hq[K_];
#pragma unroll
            for (int qq = 0; qq < K_; ++qq) hq[qq] = 0.f;
#pragma unroll
            for (int k = 0; k < K_; ++k) {
                const float hnk = hn[k];
                const float4* p4 = (const float4*)(p_s[gidx] + k * K_);
#pragma unroll
                for (int j = 0; j < 4; ++j) {
                    float4 v = p4[j];
                    hq[4*j  ] = fmaf(hnk, v.x, hq[4*j  ]);
                    hq[4*j+1] = fmaf(hnk, v.y, hq[4*j+1]);
                    hq[4*j+2] = fmaf(hnk, v.z, hq[4*j+2]);
                    hq[4*j+3] = fmaf(hnk, v.w, hq[4*j+3]);
                }
            }
            float res = -__builtin_huge_valf();
#pragma unroll
            for (int j = 0; j < 4; ++j) {
                float4 sc = ((const float4*)scal_s[gidx])[j];
                float4 rd = ((const float4*)rden_s[gidx])[j];
                res = fmaxf(res, sc.x * (hq[4*j  ] * rd.x));
                res = fmaxf(res, sc.y * (hq[4*j+1] * rd.y));
                res = fmaxf(res, sc.z * (hq[4*j+2] * rd.z));
                res = fmaxf(res, sc.w * (hq[4*j+3] * rd.w));
            }
            out[n * COUT + lo] = res;
            __builtin_amdgcn_wave_barrier();   // epilogue -> next-iter staging
        } else {
            __builtin_amdgcn_wave_barrier();   // compute -> next-iter staging
        }
    }

    if constexpr (PHA) {
        if constexpr (COUT == 32) {
            // fold the two half-wave groups (shuffle across lane 32 boundary)
            long long bs = __double_as_longlong(lsum);
            int l0 = __shfl_xor((int)(bs & 0xffffffffLL), 32, 64);
            int h0 = __shfl_xor((int)(bs >> 32), 32, 64);
            lsum += __longlong_as_double(((long long)h0 << 32) | (unsigned long long)(unsigned int)l0);
            bs = __double_as_longlong(lsq);
            l0 = __shfl_xor((int)(bs & 0xffffffffLL), 32, 64);
            h0 = __shfl_xor((int)(bs >> 32), 32, 64);
            lsq += __longlong_as_double(((long long)h0 << 32) | (unsigned long long)(unsigned int)l0);
        }
        __shared__ double redS[4][COUT];
        __shared__ double redQ[4][COUT];
        if (lane < COUT) { redS[wave][lane] = lsum; redQ[wave][lane] = lsq; }
        __syncthreads();
        if (tid < COUT) {
            double ss = redS[0][tid] + redS[1][tid] + redS[2][tid] + redS[3][tid];
            double qq = redQ[0][tid] + redQ[1][tid] + redQ[2][tid] + redQ[3][tid];
            atomicAdd(&gsum[tid], ss);
            atomicAdd(&gsumsq[tid], qq);
        }
    }
}

__global__ void finalize_kernel(const double* __restrict__ gsum, const double* __restrict__ gsumsq,
                                const float* __restrict__ gamma, const float* __restrict__ beta,
                                float* __restrict__ a, float* __restrict__ c, int cout)
{
    int o = threadIdx.x;
    if (o < cout) {
        const double inv = 1.0 / ((double)N_ * (double)K_);
        double mu  = gsum[o] * inv;
        double var = gsumsq[o] * inv - mu * mu;
        double rs  = 1.0 / sqrt(var + (double)EPS_);
        double av  = rs * (double)gamma[o];
        a[o] = (float)av;
        c[o] = (float)((double)beta[o] - mu * av);
    }
}

__global__ __launch_bounds__(256) void copy_vc(const float4* __restrict__ src,
                                               float4* __restrict__ dst) {
    int i = blockIdx.x * 256 + threadIdx.x;
    dst[i] = src[i];
}

extern "C" void kernel_launch(void* const* d_in, const int* in_sizes, int n_in,
                              void* d_out, int out_size, void* d_ws, size_t ws_size,
                              hipStream_t stream)
{
    const float* pillar = (const float*)d_in[0];
    const float* vc     = (const float*)d_in[1];
    const float* W0  = (const float*)d_in[2];
    const float* b0  = (const float*)d_in[3];
    const float* g0  = (const float*)d_in[4];
    const float* be0 = (const float*)d_in[5];
    const float* wk0 = (const float*)d_in[6];
    const float* wq0 = (const float*)d_in[7];
    const float* W1  = (const float*)d_in[8];
    const float* b1  = (const float*)d_in[9];
    const float* g1  = (const float*)d_in[10];
    const float* be1 = (const float*)d_in[11];
    const float* wk1 = (const float*)d_in[12];
    const float* wq1 = (const float*)d_in[13];

    // ---- workspace (< 16 MiB total) ----
    char* ws = (char*)d_ws;
    double* dsum = (double*)ws;                              // 2 KB @ 0
    double *s0 = dsum, *sq0 = dsum + 64, *s1 = dsum + 128, *sq1 = dsum + 192;
    float* coef = (float*)(ws + 4096);                       // 1 KB @ 4K
    float *a0 = coef, *c0 = coef + 64, *a1 = coef + 128, *c1 = coef + 192;
    unsigned short* idx = (unsigned short*)(ws + 8192);      // 2 MB
    float* d2  = (float*)(ws + 8192 + (size_t)N_*K_*2);      // 4 MB
    float* x1  = (float*)(ws + 8192 + (size_t)N_*K_*6);      // 8 MB
    size_t base2 = 8192 + (size_t)N_*K_*6 + (size_t)N_*32*4; // = 14 MB + 8 KB
    float4* pos4s = (float4*)(ws + base2);                   // 1 MB
    int* counts   = (int*)(ws + base2 + (1u<<20));           // 32 KB
    int* cursors  = counts + B_*NBK;                         // 32 KB
    int* off      = cursors + B_*NBK;                        // 8*1025*4
    int* xminI    = off + B_*(NBK+1);                        // 32 KB
    int* xmaxI    = xminI + B_*NBK;                          // 32 KB
    float* xlub   = (float*)(xmaxI + B_*NBK);                // 32 KB
    float* xglb   = xlub + B_*NBK;                           // 32 KB

    float* xout = (float*)d_out;
    float* vout = xout + (size_t)N_ * 64;

    hipMemsetAsync(dsum, 0, 2048, stream);
    init_bins<<<B_*NBK/256, 256, 0, stream>>>(counts, cursors, xminI, xmaxI);
    count_kernel<<<N_/256, 256, 0, stream>>>(vc, counts, xminI, xmaxI);
    scan_kernel<<<B_, NBK, 0, stream>>>(counts, xminI, xmaxI, off, xlub, xglb);
    scatter_kernel<<<N_/256, 256, 0, stream>>>(vc, off, cursors, pos4s);
    knn3_kernel<<<N_/256, 256, 0, stream>>>(pos4s, xlub, xglb, idx, d2);

    edge_kernel<4,32,true ><<<1024, 256, 0, stream>>>(pillar, idx, d2, W0, b0, wk0, wq0,
                                                      nullptr, nullptr, s0, sq0, nullptr, 8);
    finalize_kernel<<<1, 64, 0, stream>>>(s0, sq0, g0, be0, a0, c0, 32);
    edge_kernel<4,32,false><<<1024, 256, 0, stream>>>(pillar, idx, d2, W0, b0, wk0, wq0,
                                                      a0, c0, nullptr, nullptr, x1, 8);

    edge_kernel<32,64,true ><<<2048, 256, 0, stream>>>(x1, idx, d2, W1, b1, wk1, wq1,
                                                       nullptr, nullptr, s1, sq1, nullptr, 8);
    finalize_kernel<<<1, 64, 0, stream>>>(s1, sq1, g1, be1, a1, c1, 64);
    edge_kernel<32,64,false><<<2048, 256, 0, stream>>>(x1, idx, d2, W1, b1, wk1, wq1,
                                                       a1, c1, nullptr, nullptr, xout, 8);

    copy_vc<<<256, 256, 0, stream>>>((const float4*)vc, (float4*)vout);
}